// Round 11
// baseline (141.042 us; speedup 1.0000x reference)
//
#include <hip/hip_runtime.h>
#include <math.h>

#define BQ 8
#define MQ 64
#define REGMAX 16
#define KTOP 10
#define EPSQ 1e-7f
#define MBUF 1344  // >= bpb*KTOP = 1330 for N=34000

__device__ __forceinline__ float frcp(float x) { return __builtin_amdgcn_rcpf(x); }

// state (floats): acc[32] = per-batch {sum(1-t), npos, bce_sum, pad}
#define ST_BYTES 256

// async global->LDS, 16 B/lane: lane l loads 16 B at its own gptr into
// (wave-uniform lds base) + l*16. Verified pattern on gfx950 (m97).
__device__ __forceinline__ void async_row16(const float* g, float* lds) {
  __builtin_amdgcn_global_load_lds(
      (const __attribute__((address_space(1))) unsigned int*)(uintptr_t)g,
      (__attribute__((address_space(3))) unsigned int*)(uintptr_t)lds, 16, 0, 0);
}

// ---------------- kernel 1: async-LDS decode + screen + per-block per-target top-10 ----------------
// grid = BQ * bpb, 256 threads; block handles 256 anchors of one batch.
// s_u (32 KB): stage[2][16][256] (phase 1)  UNION  s_hv[2560] | s_hi[2560] | s_mg[640]u2 (phases 2-3)
__global__ __launch_bounds__(256) void decode_topk_kernel(
    const float* __restrict__ boxes, const float* __restrict__ scores,
    const float* __restrict__ targets, unsigned int* __restrict__ iou_bits,
    uint2* __restrict__ cand, float* __restrict__ acc, int N, int bpb) {
  const int tid = threadIdx.x;
  const int b = blockIdx.x / bpb;
  const int blk = blockIdx.x - b * bpb;
  const int a0 = blk * 256;
  const int w = tid >> 6;
  const int l = tid & 63;

  __shared__ float s_u[8192];  // 32 KB
  float (*stage)[16][256] = (float (*)[16][256])s_u;
  float* s_hv = s_u;                    // 2560 floats
  int* s_hi = (int*)(s_u + 2560);       // 2560 ints
  uint2* s_mg = (uint2*)(s_u + 5120);   // 640 uint2

  __shared__ float4 s_sv[256];
  __shared__ float s_at[256];
  __shared__ int s_ix[256];
  __shared__ int s_cnt;
  __shared__ float s_bce;
  if (tid == 0) { s_cnt = 0; s_bce = 0.f; }

  // ---- phase 1: ping-pong async staging of the 4 sides (16 rows = 16 KB each) ----
  const size_t Ns = (size_t)N;
  // per-lane float offset of this lane's 16B chunk, clamped so the tail block
  // never reads past the tensor (boxes ends exactly on a page boundary).
  const int off = min(l * 4, N - a0 - 4);
  const float* bbase = boxes + (size_t)(b * 64) * Ns + a0;

  {  // issue side 0 -> buf 0 (wave w stages rows r = 4i+w)
#pragma unroll
    for (int i = 0; i < 4; ++i) {
      const int r = 4 * i + w;
      async_row16(bbase + (size_t)r * Ns + off, &stage[0][r][0]);
    }
  }
  __syncthreads();

  float ev[4];
  int buf = 0;
#pragma unroll
  for (int k = 0; k < 4; ++k) {
    if (k < 3) {  // issue side k+1 into the spare buffer; flight overlaps consume
      const float* sb = bbase + (size_t)((k + 1) * 16) * Ns;
#pragma unroll
      for (int i = 0; i < 4; ++i) {
        const int r = 4 * i + w;
        async_row16(sb + (size_t)r * Ns + off, &stage[buf ^ 1][r][0]);
      }
    }
    float x[REGMAX];
#pragma unroll
    for (int r = 0; r < REGMAX; ++r) x[r] = stage[buf][r][tid];  // 2-way = free
    float mx = x[0];
#pragma unroll
    for (int r = 1; r < REGMAX; ++r) mx = fmaxf(mx, x[r]);
    float s = 0.f, ws = 0.f;
#pragma unroll
    for (int r = 0; r < REGMAX; ++r) {
      float e = __expf(x[r] - mx);
      s += e;
      ws += (float)r * e;
    }
    ev[k] = ws * frcp(s);
    __syncthreads();  // drains side k+1 loads; releases stage[buf] for reuse
    buf ^= 1;
  }

  // ---- phase 1b: screen + compact survivors + bce(s,0) + iou zero ----
  const int n = a0 + tid;
  float bce0 = 0.f;
  if (n < N) {
    const size_t i = (size_t)b * N + n;
    iou_bits[i] = 0u;
    float sc = scores[i];
    bce0 = fmaxf(sc, 0.f) + log1pf(__expf(-fabsf(sc)));
    float w1 = ev[2] - ev[0], h1 = ev[3] - ev[1];
    if (w1 > 0.f && h1 > 0.f) {  // else ciou<=0 vs every target: reference masks topv>0
      int slot = atomicAdd(&s_cnt, 1);
      s_sv[slot] = make_float4(ev[0], ev[1], ev[2], ev[3]);
      s_at[slot] = atanf(w1 * frcp(h1 + EPSQ));
      s_ix[slot] = n;
    }
  }
#pragma unroll
  for (int d = 1; d < 64; d <<= 1) bce0 += __shfl_xor(bce0, d, 64);
  if (l == 0) atomicAdd(&s_bce, bce0);
  __syncthreads();
  const int nsurv = s_cnt;
  if (tid == 0) atomicAdd(&acc[b * 4 + 2], s_bce);

  // ---- phase 2: lane = target; wave w scans its survivor quarter (LDS broadcast) ----
  const float4 t = ((const float4*)targets)[b * MQ + l];
  const float x21 = t.x, y21 = t.y, x22 = t.z, y22 = t.w;
  const float w2 = x22 - x21, h2 = y22 - y21;
  const float atan_t = atanf(w2 * frcp(h2 + EPSQ));
  const float area2 = w2 * h2, sumx2 = x21 + x22, sumy2 = y21 + y22;
  const float CPI = 4.0f / (float)(M_PI * M_PI);

  float hv0 = 0.f, hv1 = 0.f, hv2 = 0.f, hv3 = 0.f, hv4 = 0.f;
  float hv5 = 0.f, hv6 = 0.f, hv7 = 0.f, hv8 = 0.f, hv9 = 0.f;
  int hi0 = 0, hi1 = 0, hi2 = 0, hi3 = 0, hi4 = 0;
  int hi5 = 0, hi6 = 0, hi7 = 0, hi8 = 0, hi9 = 0;

  const int qlen = (nsurv + 3) >> 2;
  const int j0 = w * qlen;
  const int j1 = min(nsurv, j0 + qlen);
  for (int j = j0; j < j1; ++j) {
    float4 p = s_sv[j];  // same addr across lanes -> LDS broadcast
    float pa = s_at[j];
    int ixj = s_ix[j];
    float x11 = p.x, y11 = p.y, x12 = p.z, y12 = p.w;
    float w1 = x12 - x11, h1 = y12 - y11;
    float iw = fmaxf(fminf(x12, x22) - fmaxf(x11, x21), 0.f);
    float ih = fmaxf(fminf(y12, y22) - fmaxf(y11, y21), 0.f);
    float inter = iw * ih;
    float uni = w1 * h1 + area2 - inter + EPSQ;
    float iou = inter * frcp(uni);
    float cw = fmaxf(x12, x22) - fminf(x11, x21);
    float ch = fmaxf(y12, y22) - fminf(y11, y21);
    float c2 = cw * cw + ch * ch + EPSQ;
    float dx = sumx2 - x11 - x12;
    float dy = sumy2 - y11 - y12;
    float rho2 = (dx * dx + dy * dy) * 0.25f;
    float da = atan_t - pa;
    float v = CPI * da * da;
    float alpha = v * frcp(v - iou + 1.f + EPSQ);
    float ciou = iou - rho2 * frcp(c2) - alpha * v;
    if (ciou > hv9) {
      float cv = ciou;
      int ci = ixj;
#define INS(vk, ik)                         \
  {                                         \
    bool gt = cv > vk;                      \
    float tv_ = vk; int ti_ = ik;           \
    vk = gt ? cv : vk; ik = gt ? ci : ik;   \
    cv = gt ? tv_ : cv; ci = gt ? ti_ : ci; \
  }
      INS(hv0, hi0) INS(hv1, hi1) INS(hv2, hi2) INS(hv3, hi3) INS(hv4, hi4)
      INS(hv5, hi5) INS(hv6, hi6) INS(hv7, hi7) INS(hv8, hi8) INS(hv9, hi9)
#undef INS
    }
  }
  const int hb = (w * MQ + l) * KTOP;  // s_hv/s_hi alias the dead stage
  s_hv[hb + 0] = hv0; s_hi[hb + 0] = hi0;
  s_hv[hb + 1] = hv1; s_hi[hb + 1] = hi1;
  s_hv[hb + 2] = hv2; s_hi[hb + 2] = hi2;
  s_hv[hb + 3] = hv3; s_hi[hb + 3] = hi3;
  s_hv[hb + 4] = hv4; s_hi[hb + 4] = hi4;
  s_hv[hb + 5] = hv5; s_hi[hb + 5] = hi5;
  s_hv[hb + 6] = hv6; s_hi[hb + 6] = hi6;
  s_hv[hb + 7] = hv7; s_hi[hb + 7] = hi7;
  s_hv[hb + 8] = hv8; s_hi[hb + 8] = hi8;
  s_hv[hb + 9] = hv9; s_hi[hb + 9] = hi9;
  __syncthreads();

  // ---- phase 3: wave 0, lane m: 4-way merge -> s_mg; coalesced copy-out ----
  if (w == 0) {
    const int m = l;
    int p0 = 0, p1 = 0, p2 = 0, p3 = 0;
    for (int r = 0; r < KTOP; ++r) {
      float c0 = s_hv[(0 * MQ + m) * KTOP + p0];
      float c1 = s_hv[(1 * MQ + m) * KTOP + p1];
      float c2m = s_hv[(2 * MQ + m) * KTOP + p2];
      float c3 = s_hv[(3 * MQ + m) * KTOP + p3];
      float best = c0; int bw = 0;
      if (c1 > best) { best = c1; bw = 1; }
      if (c2m > best) { best = c2m; bw = 2; }
      if (c3 > best) { best = c3; bw = 3; }
      int psel = (bw == 0) ? p0 : (bw == 1) ? p1 : (bw == 2) ? p2 : p3;
      int bidx = s_hi[(bw * MQ + m) * KTOP + psel];
      s_mg[m * KTOP + r] = make_uint2(__float_as_uint(best), (unsigned)bidx);
      if (bw == 0) p0 = min(p0 + 1, KTOP - 1);
      else if (bw == 1) p1 = min(p1 + 1, KTOP - 1);
      else if (bw == 2) p2 = min(p2 + 1, KTOP - 1);
      else p3 = min(p3 + 1, KTOP - 1);
    }
  }
  __syncthreads();
  uint2* obase = cand + (size_t)(b * bpb + blk) * (MQ * KTOP);
  for (int sl = tid; sl < MQ * KTOP; sl += 256) obase[sl] = s_mg[sl];
}

// ---------------- exact top-10 of LDS buffer (wave 0 only) ----------------
__device__ __forceinline__ void select_top10(
    float* s_bv, int* s_bi, float* s_winv, int* s_wini,
    int* s_cnt, int c, int tid) {
  if (tid < 64) {
    for (int r = 0; r < KTOP; ++r) {
      float bv = 0.f;
      int bs = 0xffff;
      for (int sl = tid; sl < c; sl += 64) {
        float v = s_bv[sl];
        if (v > bv) { bv = v; bs = sl; }
      }
      unsigned long long key =
          ((unsigned long long)__float_as_uint(bv) << 32) | (unsigned int)bs;
#pragma unroll
      for (int d = 1; d < 64; d <<= 1) {
        unsigned long long o = __shfl_xor(key, d, 64);
        if (o > key) key = o;
      }
      if (tid == 0) {
        float wv = __uint_as_float((unsigned int)(key >> 32));
        int ws = (int)(key & 0xffffu);
        s_winv[r] = wv;
        if (wv > 0.f && ws != 0xffff) {
          s_wini[r] = s_bi[ws];
          s_bv[ws] = 0.f;
        } else {
          s_wini[r] = 0;
        }
      }
    }
    if (tid < KTOP) { s_bv[tid] = s_winv[tid]; s_bi[tid] = s_wini[tid]; }
    if (tid == 0) *s_cnt = KTOP;
  }
}

// ---------------- kernel 2: merge 133x10 per (b,m) -> top-10; scatter + exact delta ----------------
__global__ __launch_bounds__(256) void merge_kernel(
    const uint2* __restrict__ cand, const float* __restrict__ scores,
    unsigned int* __restrict__ iou_bits, float* __restrict__ acc,
    int N, int bpb) {
  const int bm = blockIdx.x;
  const int b = bm >> 6;
  const int m = bm & 63;
  const int tid = threadIdx.x;
  const int NC = bpb * KTOP;  // 1330 for N=34000

  __shared__ float s_bv[MBUF];
  __shared__ int s_bi[MBUF];
  __shared__ float s_winv[KTOP];
  __shared__ int s_wini[KTOP];
  __shared__ int s_cnt;
  if (tid == 0) s_cnt = 0;
  __syncthreads();

  for (int k2 = tid; k2 < NC; k2 += 256) {
    int blkk = k2 / KTOP;
    int r = k2 - blkk * KTOP;
    uint2 e = cand[((size_t)(b * bpb + blkk) * MQ + m) * KTOP + r];
    float v = __uint_as_float(e.x);
    if (v > 0.f) {
      int slot = atomicAdd(&s_cnt, 1);  // slot < NC <= MBUF
      s_bv[slot] = v;
      s_bi[slot] = (int)e.y;
    }
  }
  __syncthreads();
  int c = s_cnt;
  __syncthreads();
  if (c > KTOP) {
    select_top10(s_bv, s_bi, s_winv, s_wini, &s_cnt, c, tid);
    __syncthreads();
    c = KTOP;
  }
  if (tid < KTOP && tid < c) {
    float v = s_bv[tid];
    if (v > 0.f) {
      int ix = s_bi[tid];
      unsigned int vb = __float_as_uint(v);
      unsigned int old = atomicMax(&iou_bits[(size_t)b * N + ix], vb);
      if (old < vb) {  // raised this anchor's max: account exact delta (telescopes)
        float vold = __uint_as_float(old);  // 0.f when old==0
        bool was = (old != 0u);
        atomicAdd(&acc[b * 4 + 0], was ? (vold - v) : (1.f - v));
        if (!was) atomicAdd(&acc[b * 4 + 1], 1.f);
        atomicAdd(&acc[b * 4 + 2], -scores[(size_t)b * N + ix] * (v - vold));
      }
    }
  }
}

// ---------------- finalize ----------------
__global__ void finalize_kernel(const float* __restrict__ acc,
                                float* __restrict__ out, int N) {
  if (threadIdx.x == 0 && blockIdx.x == 0) {
    float box = 0.f, obj = 0.f;
    for (int bb = 0; bb < BQ; ++bb) {
      float sb = acc[bb * 4 + 0];
      float np = acc[bb * 4 + 1];
      float sc = acc[bb * 4 + 2];
      box += (np > 0.f) ? sb / fmaxf(np, 1.f) : 0.f;
      obj += sc / (float)N;
    }
    out[0] = (7.5f * box + obj) / (float)BQ;
    out[1] = box;
    out[2] = obj;
  }
}

extern "C" void kernel_launch(void* const* d_in, const int* in_sizes, int n_in,
                              void* d_out, int out_size, void* d_ws, size_t ws_size,
                              hipStream_t stream) {
  const float* boxes = (const float*)d_in[0];
  const float* scores = (const float*)d_in[1];
  const float* targets = (const float*)d_in[2];
  float* out = (float*)d_out;
  const int N = in_sizes[1] / BQ;  // scores is [B, N]; N % 4 == 0

  const int bpb = (N + 255) / 256;  // 133

  char* ws = (char*)d_ws;
  size_t cand_bytes = (size_t)BQ * bpb * MQ * KTOP * sizeof(uint2);
  size_t iou_bytes = (size_t)BQ * N * sizeof(unsigned int);

  uint2* cand = (uint2*)ws;                    ws += cand_bytes;
  unsigned int* iou_bits = (unsigned int*)ws;  ws += iou_bytes;
  float* state = (float*)ws;                   // ST_BYTES

  hipMemsetAsync(state, 0, ST_BYTES, stream);

  decode_topk_kernel<<<BQ * bpb, 256, 0, stream>>>(boxes, scores, targets,
                                                   iou_bits, cand, state, N, bpb);
  merge_kernel<<<BQ * MQ, 256, 0, stream>>>(cand, scores, iou_bits, state, N, bpb);
  finalize_kernel<<<1, 64, 0, stream>>>(state, out, N);
}